// Round 1
// 192.740 us; speedup vs baseline: 1.0596x; 1.0596x over previous
//
#include <hip/hip_runtime.h>
#include <math.h>

// ConvBertLightConv: dynamic depthwise conv with softmax-normalized per-(pos,head) kernels.
// B=8, S=4096, D=768 (12 heads x 64), K=9, 'same' zero padding along S.
// out[b,s,h,d] = sum_k softmax(filters[b,s,h,:])[k] * x[b, s+k-4, h*64+d]
//
// R3: latency/occupancy attack.
//  - TTILE 32->16: grid 1024->2048 blocks -> 8 blocks/CU -> ~24 waves/CU
//    (occupancy was grid-limited at 33%).
//  - Filter tile staged in LDS via coalesced loads; softmax computed ONCE per
//    (s,head) pair (192 pairs == 192 threads) instead of redundantly by all 16
//    threads of a head from 9 scalar global loads per iteration. Inner loop
//    reads weights via LDS broadcast (16 lanes/head -> same address, conflict-free).
//  - Sliding 9-row register window kept from R2 (x fetched ~1.5x, halo L2/L3-hit).

#define KS 9
#define HD 64
#define NH 12
#define DMODEL 768          // NH*HD
#define SEQ 4096
#define BATCH 8
#define TTILE 16            // s-positions per block
#define CHUNKS (SEQ / TTILE)   // 256
#define FSTRIDE (NH * KS)   // 108 filter floats per position
#define NTHREADS 192

__global__ __launch_bounds__(NTHREADS, 6) void lightconv_kernel(
    const float* __restrict__ x,      // [B, S, 768]
    const float* __restrict__ filt,   // [B, S, 108]
    float* __restrict__ out)          // [B, S, 768]
{
    __shared__ float wlds[TTILE * FSTRIDE];   // 16*108*4B = 6912 B

    const int blk   = blockIdx.x;             // b * CHUNKS + chunk
    const int chunk = blk & (CHUNKS - 1);
    const int b     = blk >> 8;               // CHUNKS = 256
    const int s0    = chunk * TTILE;
    const int t     = threadIdx.x;            // 0..191

    // ---- Phase 1: coalesced stage of filter tile [TTILE][108] into LDS ----
    const float* fbase = filt + ((size_t)b * SEQ + s0) * FSTRIDE;
#pragma unroll
    for (int i = 0; i < (TTILE * FSTRIDE) / NTHREADS; ++i) {   // 9 iters
        const int idx = t + i * NTHREADS;     // 0..1727, stride-1 across lanes
        wlds[idx] = fbase[idx];
    }
    __syncthreads();

    // ---- Phase 2: one softmax per (s_local, head); 192 pairs == 192 threads ----
    {
        const int sl = t & 15;                // s_local 0..15
        const int hh = t >> 4;                // head    0..11
        float* wp = &wlds[sl * FSTRIDE + hh * KS];
        float w[KS];
        float m = -1e30f;
#pragma unroll
        for (int k = 0; k < KS; ++k) { w[k] = wp[k]; m = fmaxf(m, w[k]); }
        float sum = 0.f;
#pragma unroll
        for (int k = 0; k < KS; ++k) { w[k] = __expf(w[k] - m); sum += w[k]; }
        const float inv = 1.0f / sum;
#pragma unroll
        for (int k = 0; k < KS; ++k) wp[k] = w[k] * inv;
    }
    __syncthreads();

    // ---- Phase 3: sliding-window conv, 9-row window in registers ----
    const int head = t >> 4;                  // 0..11
    const int d4   = (t & 15) << 2;           // 0,4,...,60

    const float* xc = x   + (size_t)b * SEQ * DMODEL + head * HD + d4;
    float*       oc = out + (size_t)b * SEQ * DMODEL + head * HD + d4;

    const float4 zero = make_float4(0.f, 0.f, 0.f, 0.f);

    // preload window rows s0-4 .. s0+3 (win[8] filled per-iteration)
    float4 win[KS];
#pragma unroll
    for (int k = 0; k < KS - 1; ++k) {
        const int ss = s0 + k - (KS / 2);     // ss <= s0+3 < SEQ always
        win[k] = (ss >= 0) ? *reinterpret_cast<const float4*>(xc + (size_t)ss * DMODEL)
                           : zero;
    }

#pragma unroll
    for (int i = 0; i < TTILE; ++i) {
        const int s  = s0 + i;
        const int ss = s + (KS / 2);          // new trailing row
        win[KS - 1] = (ss < SEQ) ? *reinterpret_cast<const float4*>(xc + (size_t)ss * DMODEL)
                                 : zero;

        // normalized weights from LDS: 16 lanes of a head read the same
        // addresses -> broadcast, no bank conflicts.
        const float* wp = &wlds[i * FSTRIDE + head * KS];

        float4 acc = zero;
#pragma unroll
        for (int k = 0; k < KS; ++k) {
            const float wk = wp[k];
            acc.x += wk * win[k].x;
            acc.y += wk * win[k].y;
            acc.z += wk * win[k].z;
            acc.w += wk * win[k].w;
        }
        *reinterpret_cast<float4*>(oc + (size_t)s * DMODEL) = acc;

        // rotate window (register renaming after full unroll)
#pragma unroll
        for (int k = 0; k < KS - 1; ++k) win[k] = win[k + 1];
    }
}

extern "C" void kernel_launch(void* const* d_in, const int* in_sizes, int n_in,
                              void* d_out, int out_size, void* d_ws, size_t ws_size,
                              hipStream_t stream) {
    const float* x    = (const float*)d_in[0];   // [8,4096,768] fp32
    const float* filt = (const float*)d_in[1];   // [8,4096,108] fp32
    float* out        = (float*)d_out;           // [8,4096,12,64] fp32

    const int grid = BATCH * CHUNKS;             // 8 * 256 = 2048 blocks
    lightconv_kernel<<<grid, NTHREADS, 0, stream>>>(x, filt, out);
}